// Round 4
// baseline (298.560 us; speedup 1.0000x reference)
//
#include <hip/hip_runtime.h>
#include <stdint.h>

// GroupedLinear: y[b, g*256+o] = sum_i x[b, g*256+i] * W[g,o,i] + bias[g,o]
// B=8192, G=16. fp32 in/out, bf16 MFMA compute.
//
// R2/R3 lesson: barrier-per-K-iter drains vmcnt(0) -> latency-bound at 42%
// duty (107-119 us vs 45 us BW floor). R4: W is K-invariant -> stage W in
// LDS ONCE (one barrier per block lifetime); stream X global->register with
// a 1-step register double-buffer. Zero barriers in the K-loop -> compiler
// emits per-buffer vmcnt(N) waits; 8 prefetch loads/wave always in flight.

#define IN_F   4096
#define OUT_F  4096
#define GIN    256
#define GOUT   256

#define BN   128          // cols per block (strip)
#define MT   128          // rows per m-tile
#define NMT  4            // m-tiles per block -> 512 rows/block
#define LDB  264          // LDS B row stride in shorts (256 + 8 pad)

using short8  = __attribute__((ext_vector_type(8))) short;
using floatx4 = __attribute__((ext_vector_type(4))) float;

// round-to-nearest-even fp32 -> bf16 (branch-free)
__device__ __forceinline__ short f2bf_rne(float f) {
    unsigned u = __builtin_bit_cast(unsigned, f);
    unsigned r = u + 0x7FFFu + ((u >> 16) & 1u);
    return (short)(r >> 16);
}

__device__ __forceinline__ short8 pack8(floatx4 f0, floatx4 f1) {
    short8 p;
    p[0] = f2bf_rne(f0[0]); p[1] = f2bf_rne(f0[1]);
    p[2] = f2bf_rne(f0[2]); p[3] = f2bf_rne(f0[3]);
    p[4] = f2bf_rne(f1[0]); p[5] = f2bf_rne(f1[1]);
    p[6] = f2bf_rne(f1[2]); p[7] = f2bf_rne(f1[3]);
    return p;
}

__global__ __launch_bounds__(256, 2)
void grouped_linear_kernel(const float* __restrict__ X,
                           const float* __restrict__ W,
                           const float* __restrict__ Bias,
                           float* __restrict__ Out) {
    // W slice for this strip: 128 cols x 256 K, bf16, row stride 264 shorts.
    // Pad makes ds_read_b128 frag reads perfectly banked (8 cyc, no excess).
    __shared__ __align__(16) short lsB[BN * LDB];   // 67.6 KB -> 2 blocks/CU

    const int t    = threadIdx.x;
    const int lane = t & 63;
    const int wave = t >> 6;
    const int wm   = wave >> 1;      // M half (0..1) -> 64 rows
    const int wn   = wave & 1;       // N half (0..1) -> 64 cols
    const int lrow = lane & 15;
    const int quad = lane >> 4;

    const int bn   = blockIdx.x & 31;    // strip: 32 strips of 128 cols
    const int mb   = blockIdx.x >> 5;    // 0..15 row-stripes of 512
    const int g    = bn >> 1;            // group
    const int nlb  = (bn & 1) * BN;      // col offset inside group's W
    const int row0 = mb * (MT * NMT);
    const int col0 = bn * BN;

    const float* Wg = W + (size_t)g * GOUT * GIN + (size_t)nlb * GIN;
    const float* Xg = X + (size_t)row0 * IN_F + g * GIN;

    // per-lane A row pointers, one per i-frag (advanced per m-tile)
    const float* pA[4];
    #pragma unroll
    for (int i = 0; i < 4; ++i)
        pA[i] = Xg + (size_t)(wm * 64 + i * 16 + lrow) * IN_F + quad * 8;

    // ---- issue step-0 A prefetch first (overlaps with B staging) ----
    floatx4 araw[2][4][2];
    #pragma unroll
    for (int i = 0; i < 4; ++i) {
        araw[0][i][0] = *(const floatx4*)(pA[i]);
        araw[0][i][1] = *(const floatx4*)(pA[i] + 4);
    }

    // ---- cooperative stage of W slice -> LDS bf16 (once per block) ----
    #pragma unroll
    for (int it = 0; it < 16; ++it) {
        int G  = it * 256 + t;          // 4096 granules of 16 B
        int n  = G >> 5;                // 0..127
        int gr = G & 31;                // granule in row
        const float* src = Wg + (size_t)n * GIN + gr * 8;
        floatx4 f0 = *(const floatx4*)src;
        floatx4 f1 = *(const floatx4*)(src + 4);
        *(short8*)&lsB[n * LDB + gr * 8] = pack8(f0, f1);
    }

    float bias[4];
    #pragma unroll
    for (int j = 0; j < 4; ++j)
        bias[j] = Bias[g * GOUT + nlb + wn * 64 + j * 16 + lrow];

    __syncthreads();   // the ONLY barrier in the kernel

    const int bbase = (wn * 64 + lrow) * LDB + quad * 8;   // shorts
    float* Outp = Out + (size_t)row0 * OUT_F + col0;

    floatx4 acc[4][4];
    #pragma unroll
    for (int i = 0; i < 4; ++i)
        #pragma unroll
        for (int j = 0; j < 4; ++j)
            acc[i][j] = (floatx4){0.f, 0.f, 0.f, 0.f};

    for (int m = 0; m < NMT; ++m) {
        #pragma unroll
        for (int kk = 0; kk < 8; ++kk) {
            // advance row pointers at the last k-step (next m-tile)
            if (kk == 7) {
                #pragma unroll
                for (int i = 0; i < 4; ++i) pA[i] += (size_t)MT * IN_F;
            }
            // prefetch next step into the other register buffer
            if (!(m == NMT - 1 && kk == 7)) {
                const int nk = (kk + 1) & 7;
                #pragma unroll
                for (int i = 0; i < 4; ++i) {
                    araw[(kk + 1) & 1][i][0] = *(const floatx4*)(pA[i] + nk * 32);
                    araw[(kk + 1) & 1][i][1] = *(const floatx4*)(pA[i] + nk * 32 + 4);
                }
            }
            // B fragments from LDS (one ds_read_b128 each)
            short8 bf[4];
            #pragma unroll
            for (int j = 0; j < 4; ++j)
                bf[j] = *(const short8*)&lsB[bbase + j * 16 * LDB + kk * 32];
            // cvt A buffer -> bf16 frags
            short8 a[4];
            #pragma unroll
            for (int i = 0; i < 4; ++i)
                a[i] = pack8(araw[kk & 1][i][0], araw[kk & 1][i][1]);
            // 16 MFMAs
            #pragma unroll
            for (int i = 0; i < 4; ++i)
                #pragma unroll
                for (int j = 0; j < 4; ++j)
                    acc[i][j] = __builtin_amdgcn_mfma_f32_16x16x32_bf16(
                        a[i], bf[j], acc[i][j], 0, 0, 0);
        }

        // ---- epilogue for this m-tile (C/D: col=lane&15, row=quad*4+reg) ----
        #pragma unroll
        for (int j = 0; j < 4; ++j) {
            int gc = wn * 64 + j * 16 + lrow;
            #pragma unroll
            for (int i = 0; i < 4; ++i) {
                int gr0 = m * MT + wm * 64 + i * 16 + quad * 4;
                floatx4 v = acc[i][j];
                #pragma unroll
                for (int rg = 0; rg < 4; ++rg)
                    Outp[(size_t)(gr0 + rg) * OUT_F + gc] = v[rg] + bias[j];
                acc[i][j] = (floatx4){0.f, 0.f, 0.f, 0.f};
            }
        }
    }
}

extern "C" void kernel_launch(void* const* d_in, const int* in_sizes, int n_in,
                              void* d_out, int out_size, void* d_ws, size_t ws_size,
                              hipStream_t stream) {
    const float* X    = (const float*)d_in[0];   // [8192, 4096]
    const float* W    = (const float*)d_in[1];   // [16, 256, 256]
    const float* Bias = (const float*)d_in[2];   // [16, 256]
    float*       Out  = (float*)d_out;           // [8192, 4096]

    dim3 grid(32 * 16);   // 32 col-strips x 16 row-stripes = 512 = 2 blocks/CU
    dim3 block(256);
    grouped_linear_kernel<<<grid, block, 0, stream>>>(X, W, Bias, Out);
}